// Round 2
// baseline (472.741 us; speedup 1.0000x reference)
//
#include <hip/hip_runtime.h>

// Problem constants: B=16, NF=64, EC=3, H=W=256, NF1=8, NF2=16
#define HW 65536           // H*W
#define NPIX (16 * HW)     // B*H*W = 1,048,576 pixels
#define PX 2               // pixels per thread
#define THREADS 256

// LDS layout for fp64-converted weights (element offsets)
#define OFF_W1 0
#define OFF_B1 24
#define OFF_W2 32
#define OFF_B2 160
#define OFF_WM 176
#define OFF_BM 1200
#define OFF_WA 1264
#define OFF_BA 2288
#define NWTOT  2352

__device__ __forceinline__ double leakyd(double x) {
    // exactly where(x>=0, x, 0.2*x): for x<0, 0.2x>x; for x>=0, x>=0.2x
    return fmax(x, 0.2 * x);
}

__global__ __launch_bounds__(THREADS) void attcnn_kernel(
    const float* __restrict__ fm,   // (16,64,256,256)
    const float* __restrict__ ex,   // (16,3,256,256)
    const float* __restrict__ w1,   // (8,3)
    const float* __restrict__ b1,   // (8,)
    const float* __restrict__ w2,   // (16,8)
    const float* __restrict__ b2,   // (16,)
    const float* __restrict__ wm,   // (64,16)
    const float* __restrict__ bm,   // (64,)
    const float* __restrict__ wa,   // (64,16)
    const float* __restrict__ ba,   // (64,)
    float* __restrict__ out)        // (16,64,256,256)
{
    __shared__ double sd[NWTOT];

    const int tid = threadIdx.x;
    // Stage weights into LDS as fp64 (exact fp32->fp64 conversion)
    if (tid < 24)  sd[OFF_W1 + tid] = (double)w1[tid];
    if (tid < 8)   sd[OFF_B1 + tid] = (double)b1[tid];
    if (tid < 128) sd[OFF_W2 + tid] = (double)w2[tid];
    if (tid < 16)  sd[OFF_B2 + tid] = (double)b2[tid];
    if (tid < 64)  { sd[OFF_BM + tid] = (double)bm[tid];
                     sd[OFF_BA + tid] = (double)ba[tid]; }
    #pragma unroll
    for (int i = 0; i < 4; ++i) {
        sd[OFF_WM + tid + i * 256] = (double)wm[tid + i * 256];
        sd[OFF_WA + tid + i * 256] = (double)wa[tid + i * 256];
    }
    __syncthreads();

    // Each thread handles PX=2 consecutive pixels (HW % 2 == 0, same batch)
    const long base = ((long)blockIdx.x * THREADS + tid) * PX;
    const int b  = (int)(base >> 16);        // base / HW
    const int hw = (int)(base & 65535);      // base % HW

    // --- Stage 1: extra_maps (3 ch) -> fea1 (8), fp64 ---
    const float* exp_ = ex + (long)b * 3 * HW + hw;
    const float2 e0 = *(const float2*)(exp_);
    const float2 e1 = *(const float2*)(exp_ + HW);
    const float2 e2 = *(const float2*)(exp_ + 2 * HW);
    const double e0d[2] = {(double)e0.x, (double)e0.y};
    const double e1d[2] = {(double)e1.x, (double)e1.y};
    const double e2d[2] = {(double)e2.x, (double)e2.y};

    double f1[8][2];
    #pragma unroll
    for (int j = 0; j < 8; ++j) {
        const double c0 = sd[OFF_W1 + j * 3 + 0];
        const double c1 = sd[OFF_W1 + j * 3 + 1];
        const double c2 = sd[OFF_W1 + j * 3 + 2];
        const double bb = sd[OFF_B1 + j];
        #pragma unroll
        for (int p = 0; p < 2; ++p)
            f1[j][p] = leakyd(fma(c0, e0d[p], fma(c1, e1d[p], fma(c2, e2d[p], bb))));
    }

    // --- Stage 2: fea1 (8) -> fea2 (16), fp64 ---
    double f2[16][2];
    #pragma unroll
    for (int k = 0; k < 16; ++k) {
        double a0 = sd[OFF_B2 + k], a1 = a0;
        #pragma unroll
        for (int j = 0; j < 8; ++j) {
            const double w = sd[OFF_W2 + k * 8 + j];
            a0 = fma(w, f1[j][0], a0);
            a1 = fma(w, f1[j][1], a1);
        }
        f2[k][0] = leakyd(a0);
        f2[k][1] = leakyd(a1);
    }

    // --- Stage 3: per output channel o: mul/add dots (fp64) + epilogue ---
    const float* fmp = fm  + (long)b * 64 * HW + hw;
    float*       op  = out + (long)b * 64 * HW + hw;

    #pragma unroll 2
    for (int o = 0; o < 64; ++o) {
        double m0 = sd[OFF_BM + o], m1 = m0;
        double a0 = sd[OFF_BA + o], a1 = a0;
        #pragma unroll
        for (int k = 0; k < 16; ++k) {
            const double wmv = sd[OFF_WM + o * 16 + k];
            const double wav = sd[OFF_WA + o * 16 + k];
            m0 = fma(wmv, f2[k][0], m0);
            m1 = fma(wmv, f2[k][1], m1);
            a0 = fma(wav, f2[k][0], a0);
            a1 = fma(wav, f2[k][1], a1);
        }
        const float2 f = *(const float2*)(fmp + (long)o * HW);
        // denom in fp64 (the sensitive part), then fp32 division
        const double den0 = fma((double)f.x, m0, 1.0);
        const double den1 = fma((double)f.y, m1, 1.0);
        float h0 = (float)den0;             // exact relative conversion
        float h1 = (float)den1;
        float r0 = __builtin_amdgcn_rcpf(h0);
        float r1 = __builtin_amdgcn_rcpf(h1);
        r0 = r0 * fmaf(-h0, r0, 2.0f);      // Newton: ~1 ulp fp32
        r1 = r1 * fmaf(-h1, r1, 2.0f);
        float2 o2;
        o2.x = (float)a0 * r0;
        o2.y = (float)a1 * r1;
        *(float2*)(op + (long)o * HW) = o2;
    }
}

extern "C" void kernel_launch(void* const* d_in, const int* in_sizes, int n_in,
                              void* d_out, int out_size, void* d_ws, size_t ws_size,
                              hipStream_t stream) {
    const float* fm = (const float*)d_in[0];
    const float* ex = (const float*)d_in[1];
    const float* w1 = (const float*)d_in[2];
    const float* b1 = (const float*)d_in[3];
    const float* w2 = (const float*)d_in[4];
    const float* b2 = (const float*)d_in[5];
    const float* wm = (const float*)d_in[6];
    const float* bm = (const float*)d_in[7];
    const float* wa = (const float*)d_in[8];
    const float* ba = (const float*)d_in[9];
    float* out = (float*)d_out;

    const int total_threads = NPIX / PX;       // 524,288
    const int blocks = total_threads / THREADS; // 2048
    attcnn_kernel<<<blocks, THREADS, 0, stream>>>(fm, ex, w1, b1, w2, b2,
                                                  wm, bm, wa, ba, out);
}